// Round 6
// baseline (137.472 us; speedup 1.0000x reference)
//
#include <hip/hip_runtime.h>
#include <hip/hip_bf16.h>

// Problem constants
#define BB 32
#define LL 2048
#define DD 64
#define TT 512
#define INV2PI 0.15915494309189535f
// H=2, P=2 -> hp index = h*2+p in [0,4)

// Workspace: partials [b][chunk][576] ; 576 = numer[4*64] denom[4*64] sumX[64]
#define NCHUNK 16
#define PSTRIDE 576

// ---------------------------------------------------------------------------
// k_attn v3. Phase order is vmcnt-aware (gfx950 VMEM completes in order):
//  1) stage ALL small inputs (ts, te_w, te_b, km_b) to LDS first,
//  2) q-prep (global qm_w, consumed immediately),
//  3) r-prep (global km_w, consumed immediately),
//  4) ISSUE full X/M tile as float4 register prefetch,
//  5) score phase (LDS/VALU only -> overlaps the in-flight stream),
//  6) accumulate from registers, reduce, float4 slot stores.
// grid (16, 32), block 256.
// ---------------------------------------------------------------------------
__global__ void __launch_bounds__(256) k_attn(
    const float* __restrict__ ts,
    const float* __restrict__ X,
    const float* __restrict__ M,
    const float* __restrict__ te_w,
    const float* __restrict__ te_b,
    const float* __restrict__ query,
    const float* __restrict__ qm_w,
    const float* __restrict__ qm_b,
    const float* __restrict__ km_w,
    const float* __restrict__ km_b,
    float* __restrict__ ws) {
  __shared__ float tsl[128], tew[128], teb[128], kmb[128];
  __shared__ float q_lds[256];
  __shared__ float r_lds[512];               // [hp][i]
  __shared__ __align__(16) float rp4[256];   // [e][hp], e = even-i/2 < 64
  __shared__ __align__(8)  float feat2[128]; // [e][2] = (w_rev, b_rev)
  __shared__ float C0[4], C1[4];
  __shared__ float sred[1024];               // [t][hp] score partials
  __shared__ __align__(16) float w_lds[512]; // [l][hp]
  __shared__ float red[256 * 36];            // 36 KB partial matrix
  const int t = threadIdx.x;
  const int b = blockIdx.y;
  const int lc = blockIdx.x * 128;

  // 1) stage small inputs (tiny, consumed-immediate loads; nothing in flight)
  if (t < 128) {
    tsl[t] = ts[(size_t)b * LL + lc + t];
    tew[t] = te_w[t];
    teb[t] = te_b[t];
    kmb[t] = km_b[t];
  }

  {  // 2) q[p][e] (t = p*128+e), 4 independent accumulators
    const int p = t >> 7, e = t & 127;
    const float* qq = query + p * 128;
    const float* qw = qm_w + e;
    float a0 = 0.f, a1 = 0.f, a2 = 0.f, a3 = 0.f;
    for (int i = 0; i < 128; i += 4) {
      a0 += qq[i]     * qw[i * 128];
      a1 += qq[i + 1] * qw[(i + 1) * 128];
      a2 += qq[i + 2] * qw[(i + 2) * 128];
      a3 += qq[i + 3] * qw[(i + 3) * 128];
    }
    q_lds[t] = (a0 + a1) + (a2 + a3) + qm_b[e];
  }
  __syncthreads();  // #1

  if (t < 64) {  // prescale even-index sin params to revolutions (LDS only)
    feat2[2 * t]     = tew[2 * t] * INV2PI;
    feat2[2 * t + 1] = teb[2 * t] * INV2PI;
  }
  for (int o = t; o < 512; o += 256) {  // 3) r[hp][i] (global km_w, consumed)
    const int hp = o >> 7, i = o & 127;
    const int h = hp >> 1, p = hp & 1;
    const float4* km4 = (const float4*)(km_w + i * 128 + h * 64);
    const float* qp = &q_lds[p * 128 + h * 64];
    float acc = 0.f;
#pragma unroll
    for (int e4 = 0; e4 < 16; ++e4) {
      const float4 w = km4[e4];
      acc += qp[4 * e4] * w.x + qp[4 * e4 + 1] * w.y +
             qp[4 * e4 + 2] * w.z + qp[4 * e4 + 3] * w.w;
    }
    r_lds[o] = acc;
  }
  __syncthreads();  // #2

  // 4) issue the FULL X/M tile as float4 register prefetch.
  //    All remaining pre-consumption compute is LDS/VALU only, so these
  //    in-order VMEM loads stream while the score phase runs.
  const int dquad = t & 15, lr = t >> 4;  // d = 4*dquad; rows lr+16*i
  const float4* X4 = (const float4*)X;
  const float4* M4 = (const float4*)M;
  const size_t base4 = ((size_t)b * LL + lc) * 16;  // float4 units per row
  float4 xa[8], ma[8];
#pragma unroll
  for (int i = 0; i < 8; ++i) {
    xa[i] = X4[base4 + (size_t)(lr + i * 16) * 16 + dquad];
    ma[i] = M4[base4 + (size_t)(lr + i * 16) * 16 + dquad];
  }

  if (t < 64) {  // pack r for the sin loop: rp4[e][hp] = r[hp][2e]
#pragma unroll
    for (int hp = 0; hp < 4; ++hp) rp4[t * 4 + hp] = r_lds[hp * 128 + 2 * t];
  }
  if (t >= 64 && t < 72) {  // closed-form odd terms (LDS only): C1=U, C0=V+c
    const int hp = (t - 64) >> 1;
    if ((t & 1) == 0) {
      float s = 0.f;
      for (int e = 0; e < 64; ++e) s += tew[2 * e + 1] * r_lds[hp * 128 + 2 * e + 1];
      C1[hp] = s;
    } else {
      float s = 0.f;
      for (int e = 0; e < 64; ++e) s += teb[2 * e + 1] * r_lds[hp * 128 + 2 * e + 1];
      const int h = hp >> 1, p = hp & 1;
      float c = 0.f;
      for (int e = 0; e < 64; ++e) c += q_lds[p * 128 + h * 64 + e] * kmb[h * 64 + e];
      C0[hp] = s + c;
    }
  }
  __syncthreads();  // #3

  {  // 5) sin partials: 2 threads/l, each 32 of the 64 even terms, all 4 hp
    const int l = t >> 1, half = t & 1;
    const float tt = tsl[l];
    const float2* f2 = (const float2*)feat2;
    const float4* r4 = (const float4*)rp4;
    float p0 = 0.f, p1 = 0.f, p2 = 0.f, p3 = 0.f;
    const int e0 = half * 32;
    for (int e = e0; e < e0 + 32; ++e) {
      const float2 wb = f2[e];
      const float f = __builtin_amdgcn_sinf(tt * wb.x + wb.y);  // sin(t*w+b)
      const float4 r = r4[e];
      p0 += f * r.x; p1 += f * r.y; p2 += f * r.z; p3 += f * r.w;
    }
    sred[t * 4 + 0] = p0; sred[t * 4 + 1] = p1;
    sred[t * 4 + 2] = p2; sred[t * 4 + 3] = p3;
  }
  __syncthreads();  // #4
  {  // combine + exp -> w_lds (scores O(0.3): no max-subtraction needed;
     // softmax is shift-invariant so this matches the reference)
    const int l = t >> 1, pr = t & 1;
    const float tt = tsl[l];
#pragma unroll
    for (int k2 = 0; k2 < 2; ++k2) {
      const int hp = pr * 2 + k2;
      const float s = sred[(2 * l) * 4 + hp] + sred[(2 * l + 1) * 4 + hp] +
                      tt * C1[hp] + C0[hp];
      w_lds[l * 4 + hp] = __expf(s * 0.125f);
    }
  }
  __syncthreads();  // #5

  // 6) accumulate from prefetched registers; one ds_read_b128 per row for w
  float n[4][4] = {}, dn[4][4] = {}, sx[4] = {};
  const float4* wl4 = (const float4*)w_lds;
#pragma unroll
  for (int i = 0; i < 8; ++i) {
    const int ll = lr + i * 16;
    const float4 xv = xa[i], mv = ma[i];
    const float4 wv = wl4[ll];  // w[ll][0..3]
    const float mx0 = mv.x * xv.x, mx1 = mv.y * xv.y,
                mx2 = mv.z * xv.z, mx3 = mv.w * xv.w;
    sx[0] += xv.x; sx[1] += xv.y; sx[2] += xv.z; sx[3] += xv.w;
    const float w0 = wv.x, w1 = wv.y, w2 = wv.z, w3 = wv.w;
    n[0][0] += w0 * mx0; n[0][1] += w0 * mx1; n[0][2] += w0 * mx2; n[0][3] += w0 * mx3;
    n[1][0] += w1 * mx0; n[1][1] += w1 * mx1; n[1][2] += w1 * mx2; n[1][3] += w1 * mx3;
    n[2][0] += w2 * mx0; n[2][1] += w2 * mx1; n[2][2] += w2 * mx2; n[2][3] += w2 * mx3;
    n[3][0] += w3 * mx0; n[3][1] += w3 * mx1; n[3][2] += w3 * mx2; n[3][3] += w3 * mx3;
    dn[0][0] += w0 * mv.x; dn[0][1] += w0 * mv.y; dn[0][2] += w0 * mv.z; dn[0][3] += w0 * mv.w;
    dn[1][0] += w1 * mv.x; dn[1][1] += w1 * mv.y; dn[1][2] += w1 * mv.z; dn[1][3] += w1 * mv.w;
    dn[2][0] += w2 * mv.x; dn[2][1] += w2 * mv.y; dn[2][2] += w2 * mv.z; dn[2][3] += w2 * mv.w;
    dn[3][0] += w3 * mv.x; dn[3][1] += w3 * mv.y; dn[3][2] += w3 * mv.z; dn[3][3] += w3 * mv.w;
  }

  {  // write 36 partials: red[t][j], j = hp*4+k (n), 16+hp*4+k (dn), 32+k (sx)
    float* rp = &red[t * 36];
#pragma unroll
    for (int hp = 0; hp < 4; ++hp)
#pragma unroll
      for (int k = 0; k < 4; ++k) { rp[hp * 4 + k] = n[hp][k]; rp[16 + hp * 4 + k] = dn[hp][k]; }
#pragma unroll
    for (int k = 0; k < 4; ++k) rp[32 + k] = sx[k];
  }
  __syncthreads();  // #6

  if (t < 144) {  // final reduce over the 16 lr-groups; float4 global stores
    int dq, j0;
    if (t < 64)        { dq = t & 15;         j0 = (t >> 4) * 4; }        // numer
    else if (t < 128)  { dq = (t - 64) & 15;  j0 = 16 + ((t - 64) >> 4) * 4; }  // denom
    else               { dq = t - 128;        j0 = 32; }                  // sumX
    float4 s; s.x = s.y = s.z = s.w = 0.f;
#pragma unroll
    for (int g = 0; g < 16; ++g) {
      const float* rp = &red[(g * 16 + dq) * 36 + j0];
      s.x += rp[0]; s.y += rp[1]; s.z += rp[2]; s.w += rp[3];
    }
    float4* slot4 = (float4*)(ws + ((size_t)b * NCHUNK + blockIdx.x) * PSTRIDE);
    slot4[t] = s;
  }
}

// ---------------------------------------------------------------------------
// k_dec: reduce 16 partial slots -> x -> coeffs (split-k over 256 thr) ->
// A,B (split-j over 128 thr) -> decode h1=relu(A+yB), out = h1@w2 + b2.
// Block x==0 writes the coeffs output. grid (8, 32), block 256.
// ---------------------------------------------------------------------------
__global__ void __launch_bounds__(256) k_dec(
    const float* __restrict__ yts,
    const float* __restrict__ out_w,
    const float* __restrict__ out_b,
    const float* __restrict__ dec_w1,
    const float* __restrict__ dec_b1,
    const float* __restrict__ dec_w2,
    const float* __restrict__ dec_b2,
    const float* __restrict__ ws,
    float* __restrict__ out) {
  __shared__ __align__(16) float acc_l[576];
  __shared__ float x_lds[512];   // [p][h*128 + dd]
  __shared__ float cred[256];
  __shared__ float c_lds[128];   // coeffs [p][j]
  __shared__ float abred[256];
  __shared__ float ABl[128];     // A[k] 0..63, B[k] 64..127
  __shared__ __align__(16) float w2l[4096];
  __shared__ float h1l[1024];
  __shared__ float b2l[64], yl[64];
  const int t = threadIdx.x;
  const int b = blockIdx.y;
  const int t0 = blockIdx.x * 64;

  {  // stage dec_w2 (16 KB) via float4
    const float4* s4 = (const float4*)dec_w2;
    float4* d4 = (float4*)w2l;
    for (int i = t; i < 1024; i += 256) d4[i] = s4[i];
  }
  if (t < 144) {  // reduce 16 chunk partials, float4-wide (576 = 144*4)
    const float4* p4 = (const float4*)(ws + (size_t)b * NCHUNK * PSTRIDE);
    float4 s; s.x = s.y = s.z = s.w = 0.f;
    for (int c = 0; c < NCHUNK; ++c) {
      const float4 v = p4[(size_t)c * 144 + t];
      s.x += v.x; s.y += v.y; s.z += v.z; s.w += v.w;
    }
    ((float4*)acc_l)[t] = s;
  }
  if (t >= 192) {
    const int k = t - 192;
    b2l[k] = dec_b2[k];
    yl[k] = yts[b * TT + t0 + k];
  }
  __syncthreads();

  {  // finalize x (t = hp*64+d); second half of value == mask -> x==1
    const int hp = t >> 6, d = t & 63;
    const int h = hp >> 1, p = hp & 1;
    const float num = acc_l[hp * 64 + d];
    const float den = acc_l[256 + hp * 64 + d];
    const float sxv = acc_l[512 + d];
    float x1, x2;
    if (den > 0.f) { x1 = num / den; x2 = 1.f; }
    else           { x1 = sxv * (1.f / (float)LL); x2 = 0.f; }  // uniform fallback
    x_lds[p * 256 + h * 128 + d] = x1;
    x_lds[p * 256 + h * 128 + 64 + d] = x2;
  }
  __syncthreads();

  {  // coeffs split-k: t = kh*128 + p*64 + j
    const int kh = t >> 7, pj = t & 127, p = pj >> 6, j = pj & 63;
    float acc = (kh == 0) ? out_b[j] : 0.f;
    const float* xp = &x_lds[p * 256 + kh * 128];
    const float* wp = out_w + (size_t)kh * 128 * 64 + j;
    for (int k = 0; k < 128; ++k) acc += xp[k] * wp[k * 64];
    cred[t] = acc;
  }
  __syncthreads();
  if (t < 128) {
    const float c = cred[t] + cred[t + 128];
    c_lds[t] = c;
    if (blockIdx.x == 0)
      out[(size_t)BB * TT * DD + b * 128 + t] = c;  // fp32 coeffs output
  }
  __syncthreads();
  if (t < 128) {  // A,B split-j: t = jh*64 + k
    const int jh = t >> 6, k = t & 63;
    float a = 0.f, bb = 0.f;
    const float* cp = &c_lds[jh * 32];
    const float* cp2 = &c_lds[64 + jh * 32];
    for (int j = 0; j < 32; ++j) {
      const float w1 = dec_w1[(jh * 32 + j) * 64 + k];
      a += cp[j] * w1;
      bb += cp2[j] * w1;
    }
    abred[t * 2] = a;
    abred[t * 2 + 1] = bb;
  }
  __syncthreads();
  if (t < 64) {
    ABl[t]      = dec_b1[t] + abred[t * 2]     + abred[(64 + t) * 2];
    ABl[64 + t] =             abred[t * 2 + 1] + abred[(64 + t) * 2 + 1];
  }
  __syncthreads();

  const int tl = t >> 4, dg = t & 15;  // 16 t's x 16 d-groups(4 d each)
  for (int it = 0; it < 4; ++it) {
    {  // phase A: h1 for 16 t's (1024 values, 4 per thread)
      int idx = t;
#pragma unroll
      for (int rr = 0; rr < 4; ++rr, idx += 256) {
        const int tl2 = idx >> 6, k = idx & 63;
        h1l[idx] = fmaxf(ABl[k] + yl[it * 16 + tl2] * ABl[64 + k], 0.f);
      }
    }
    __syncthreads();
    {  // phase B: out tile
      float a0 = b2l[dg * 4], a1 = b2l[dg * 4 + 1],
            a2 = b2l[dg * 4 + 2], a3 = b2l[dg * 4 + 3];
      const float4* w4 = (const float4*)w2l;
      const float* h1p = &h1l[tl * 64];
      for (int k = 0; k < 64; ++k) {
        const float h = h1p[k];
        const float4 w = w4[k * 16 + dg];
        a0 += h * w.x; a1 += h * w.y; a2 += h * w.z; a3 += h * w.w;
      }
      const int tg = t0 + it * 16 + tl;
      const size_t off = ((size_t)b * TT + tg) * 64 + dg * 4;
      float4 o; o.x = a0; o.y = a1; o.z = a2; o.w = a3;
      *(float4*)(out + off) = o;
    }
    __syncthreads();
  }
}

// ---------------------------------------------------------------------------
extern "C" void kernel_launch(void* const* d_in, const int* in_sizes, int n_in,
                              void* d_out, int out_size, void* d_ws, size_t ws_size,
                              hipStream_t stream) {
  const float* ts     = (const float*)d_in[0];
  const float* X      = (const float*)d_in[1];
  const float* M      = (const float*)d_in[2];
  const float* yts    = (const float*)d_in[3];
  const float* te_w   = (const float*)d_in[4];
  const float* te_b   = (const float*)d_in[5];
  const float* query  = (const float*)d_in[6];
  const float* qm_w   = (const float*)d_in[7];
  const float* qm_b   = (const float*)d_in[8];
  const float* km_w   = (const float*)d_in[9];
  const float* km_b   = (const float*)d_in[10];
  const float* out_w  = (const float*)d_in[11];
  const float* out_b  = (const float*)d_in[12];
  const float* dec_w1 = (const float*)d_in[13];
  const float* dec_b1 = (const float*)d_in[14];
  const float* dec_w2 = (const float*)d_in[15];
  const float* dec_b2 = (const float*)d_in[16];
  float* ws = (float*)d_ws;
  float* out = (float*)d_out;

  k_attn<<<dim3(NCHUNK, BB), 256, 0, stream>>>(
      ts, X, M, te_w, te_b, query, qm_w, qm_b, km_w, km_b, ws);
  k_dec<<<dim3(TT / 64, BB), 256, 0, stream>>>(
      yts, out_w, out_b, dec_w1, dec_b1, dec_w2, dec_b2, ws, out);
}

// Round 7
// 131.924 us; speedup vs baseline: 1.0421x; 1.0421x over previous
//
#include <hip/hip_runtime.h>
#include <hip/hip_bf16.h>

// Problem constants
#define BB 32
#define LL 2048
#define DD 64
#define TT 512
#define INV2PI 0.15915494309189535f
// H=2, P=2 -> hp index = h*2+p in [0,4)

// Workspace: partials [b][chunk][576] ; 576 = numer[4*64] denom[4*64] sumX[64]
#define NCHUNK 16
#define PSTRIDE 576

// ---------------------------------------------------------------------------
// k_attn (R5 structure — best measured). Per block (128 l's, batch b):
//   q = query@qm_w + qm_b ; r[hp][i] = q . km_w cols ; odd-index (linear)
//   features folded to closed form t*C1+C0 ; even-index sin terms via
//   v_sin_f32 on prescaled revolutions. Then exp -> masked weighted sums.
// NOTE (R6 lesson): do NOT register-prefetch X/M across barriers — the
// compiler drains vmcnt(0) at every s_barrier, so the prefetch buys nothing
// and the VGPR/LDS pressure costs ~3 µs. Short-lived float2 loads in the
// accumulate loop overlap naturally across 8 resident waves.
// grid (16, 32), block 256.
// ---------------------------------------------------------------------------
__global__ void __launch_bounds__(256) k_attn(
    const float* __restrict__ ts,
    const float* __restrict__ X,
    const float* __restrict__ M,
    const float* __restrict__ te_w,
    const float* __restrict__ te_b,
    const float* __restrict__ query,
    const float* __restrict__ qm_w,
    const float* __restrict__ qm_b,
    const float* __restrict__ km_w,
    const float* __restrict__ km_b,
    float* __restrict__ ws) {
  __shared__ float q_lds[256];
  __shared__ float r_lds[512];               // [hp][i]
  __shared__ __align__(16) float rp4[256];   // [e][hp], e = even-i/2 < 64
  __shared__ __align__(8)  float feat2[128]; // [e][2] = (w_rev, b_rev)
  __shared__ float tsl[128];
  __shared__ float C0[4], C1[4];
  __shared__ float sred[1024];               // [t][hp] score partials
  __shared__ float w_lds[512];               // [l][hp]
  __shared__ float red[256 * 18];
  const int t = threadIdx.x;
  const int b = blockIdx.y;
  const int lc = blockIdx.x * 128;

  if (t < 128) tsl[t] = ts[(size_t)b * LL + lc + t];
  if (t < 64) {  // prescale even-index sin params to revolutions
    feat2[2 * t]     = te_w[2 * t] * INV2PI;
    feat2[2 * t + 1] = te_b[2 * t] * INV2PI;
  }

  {  // q[p][e] (t = p*128+e), 4 independent accumulators
    const int p = t >> 7, e = t & 127;
    const float* qq = query + p * 128;
    const float* qw = qm_w + e;
    float a0 = 0.f, a1 = 0.f, a2 = 0.f, a3 = 0.f;
    for (int i = 0; i < 128; i += 4) {
      a0 += qq[i]     * qw[i * 128];
      a1 += qq[i + 1] * qw[(i + 1) * 128];
      a2 += qq[i + 2] * qw[(i + 2) * 128];
      a3 += qq[i + 3] * qw[(i + 3) * 128];
    }
    q_lds[t] = (a0 + a1) + (a2 + a3) + qm_b[e];
  }

  // prefetch first half of this block's X/M rows into registers
  const int dpair = t & 31, lr = t >> 5;
  const float2* X2 = (const float2*)X;
  const float2* M2 = (const float2*)M;
  const size_t base = ((size_t)b * LL + lc) * 32;  // float2 units per row
  float2 xa[8], ma[8];
#pragma unroll
  for (int i = 0; i < 8; ++i) {
    xa[i] = X2[base + (size_t)(lr + i * 8) * 32 + dpair];
    ma[i] = M2[base + (size_t)(lr + i * 8) * 32 + dpair];
  }
  __syncthreads();

  for (int o = t; o < 512; o += 256) {  // r[hp][i]
    const int hp = o >> 7, i = o & 127;
    const int h = hp >> 1, p = hp & 1;
    const float4* km4 = (const float4*)(km_w + i * 128 + h * 64);
    const float* qp = &q_lds[p * 128 + h * 64];
    float acc = 0.f;
#pragma unroll
    for (int e4 = 0; e4 < 16; ++e4) {
      const float4 w = km4[e4];
      acc += qp[4 * e4] * w.x + qp[4 * e4 + 1] * w.y +
             qp[4 * e4 + 2] * w.z + qp[4 * e4 + 3] * w.w;
    }
    r_lds[o] = acc;
  }
  __syncthreads();

  if (t < 64) {  // pack r for the sin loop: rp4[e][hp] = r[hp][2e]
#pragma unroll
    for (int hp = 0; hp < 4; ++hp) rp4[t * 4 + hp] = r_lds[hp * 128 + 2 * t];
  }
  if (t >= 64 && t < 72) {  // closed-form odd terms: C1 = U, C0 = V + c
    const int hp = (t - 64) >> 1;
    if ((t & 1) == 0) {
      float s = 0.f;
      for (int e = 0; e < 64; ++e) s += te_w[2 * e + 1] * r_lds[hp * 128 + 2 * e + 1];
      C1[hp] = s;
    } else {
      float s = 0.f;
      for (int e = 0; e < 64; ++e) s += te_b[2 * e + 1] * r_lds[hp * 128 + 2 * e + 1];
      const int h = hp >> 1, p = hp & 1;
      float c = 0.f;
      for (int e = 0; e < 64; ++e) c += q_lds[p * 128 + h * 64 + e] * km_b[h * 64 + e];
      C0[hp] = s + c;
    }
  }
  __syncthreads();

  {  // sin partials: 2 threads/l, each 32 of the 64 even terms, all 4 hp
    const int l = t >> 1, half = t & 1;
    const float tt = tsl[l];
    const float2* f2 = (const float2*)feat2;
    const float4* r4 = (const float4*)rp4;
    float p0 = 0.f, p1 = 0.f, p2 = 0.f, p3 = 0.f;
    const int e0 = half * 32;
    for (int e = e0; e < e0 + 32; ++e) {
      const float2 wb = f2[e];
      const float f = __builtin_amdgcn_sinf(tt * wb.x + wb.y);  // sin(t*w+b)
      const float4 r = r4[e];
      p0 += f * r.x; p1 += f * r.y; p2 += f * r.z; p3 += f * r.w;
    }
    sred[t * 4 + 0] = p0; sred[t * 4 + 1] = p1;
    sred[t * 4 + 2] = p2; sred[t * 4 + 3] = p3;
  }
  __syncthreads();
  {  // combine + exp -> w_lds (scores O(0.3): no max-subtraction needed;
     // softmax is shift-invariant so this matches the reference)
    const int l = t >> 1, pr = t & 1;
    const float tt = tsl[l];
#pragma unroll
    for (int k2 = 0; k2 < 2; ++k2) {
      const int hp = pr * 2 + k2;
      const float s = sred[(2 * l) * 4 + hp] + sred[(2 * l + 1) * 4 + hp] +
                      tt * C1[hp] + C0[hp];
      w_lds[l * 4 + hp] = __expf(s * 0.125f);
    }
  }
  __syncthreads();

  // accumulate: lr row-group of 8, dpair -> d = 2*dpair
  float n[4][2] = {}, dn[4][2] = {}, sx[2] = {};
#pragma unroll
  for (int i = 0; i < 8; ++i) {  // prefetched half
    const int ll = lr + i * 8;
    const float2 xv = xa[i], mv = ma[i];
    const float mx0 = mv.x * xv.x, mx1 = mv.y * xv.y;
    sx[0] += xv.x; sx[1] += xv.y;
#pragma unroll
    for (int hp = 0; hp < 4; ++hp) {
      const float w = w_lds[ll * 4 + hp];
      n[hp][0]  += w * mx0;  n[hp][1]  += w * mx1;
      dn[hp][0] += w * mv.x; dn[hp][1] += w * mv.y;
    }
  }
  for (int i = 8; i < 16; ++i) {  // streamed half
    const int ll = lr + i * 8;
    const float2 xv = X2[base + (size_t)ll * 32 + dpair];
    const float2 mv = M2[base + (size_t)ll * 32 + dpair];
    const float mx0 = mv.x * xv.x, mx1 = mv.y * xv.y;
    sx[0] += xv.x; sx[1] += xv.y;
#pragma unroll
    for (int hp = 0; hp < 4; ++hp) {
      const float w = w_lds[ll * 4 + hp];
      n[hp][0]  += w * mx0;  n[hp][1]  += w * mx1;
      dn[hp][0] += w * mv.x; dn[hp][1] += w * mv.y;
    }
  }

#pragma unroll
  for (int hp = 0; hp < 4; ++hp) {
    red[t * 18 + hp * 2 + 0] = n[hp][0];
    red[t * 18 + hp * 2 + 1] = n[hp][1];
    red[t * 18 + 8 + hp * 2 + 0] = dn[hp][0];
    red[t * 18 + 8 + hp * 2 + 1] = dn[hp][1];
  }
  red[t * 18 + 16] = sx[0];
  red[t * 18 + 17] = sx[1];
  __syncthreads();

  if (t < 32) {
    float* slot = ws + ((size_t)b * NCHUNK + blockIdx.x) * PSTRIDE;
    for (int j = 0; j < 18; ++j) {
      float s = 0.f;
#pragma unroll
      for (int r2 = 0; r2 < 8; ++r2) s += red[(r2 * 32 + t) * 18 + j];
      if (j < 8) {
        const int hp = j >> 1, half = j & 1;
        slot[hp * 64 + 2 * t + half] = s;
      } else if (j < 16) {
        const int j2 = j - 8, hp = j2 >> 1, half = j2 & 1;
        slot[256 + hp * 64 + 2 * t + half] = s;
      } else {
        slot[512 + 2 * t + (j - 16)] = s;
      }
    }
  }
}

// ---------------------------------------------------------------------------
// k_dec: reduce 16 partial slots -> x -> coeffs (split-k over 256 thr) ->
// A,B (split-j over 128 thr) -> decode h1=relu(A+yB), out = h1@w2 + b2.
// Block x==0 writes the coeffs output. grid (8, 32), block 256.
// ---------------------------------------------------------------------------
__global__ void __launch_bounds__(256) k_dec(
    const float* __restrict__ yts,
    const float* __restrict__ out_w,
    const float* __restrict__ out_b,
    const float* __restrict__ dec_w1,
    const float* __restrict__ dec_b1,
    const float* __restrict__ dec_w2,
    const float* __restrict__ dec_b2,
    const float* __restrict__ ws,
    float* __restrict__ out) {
  __shared__ __align__(16) float acc_l[576];
  __shared__ float x_lds[512];   // [p][h*128 + dd]
  __shared__ float cred[256];
  __shared__ float c_lds[128];   // coeffs [p][j]
  __shared__ float abred[256];
  __shared__ float ABl[128];     // A[k] 0..63, B[k] 64..127
  __shared__ __align__(16) float w2l[4096];
  __shared__ float h1l[1024];
  __shared__ float b2l[64], yl[64];
  const int t = threadIdx.x;
  const int b = blockIdx.y;
  const int t0 = blockIdx.x * 64;

  {  // stage dec_w2 (16 KB) via float4
    const float4* s4 = (const float4*)dec_w2;
    float4* d4 = (float4*)w2l;
    for (int i = t; i < 1024; i += 256) d4[i] = s4[i];
  }
  if (t < 144) {  // reduce 16 chunk partials, float4-wide (576 = 144*4)
    const float4* p4 = (const float4*)(ws + (size_t)b * NCHUNK * PSTRIDE);
    float4 s; s.x = s.y = s.z = s.w = 0.f;
    for (int c = 0; c < NCHUNK; ++c) {
      const float4 v = p4[(size_t)c * 144 + t];
      s.x += v.x; s.y += v.y; s.z += v.z; s.w += v.w;
    }
    ((float4*)acc_l)[t] = s;
  }
  if (t >= 192) {
    const int k = t - 192;
    b2l[k] = dec_b2[k];
    yl[k] = yts[b * TT + t0 + k];
  }
  __syncthreads();

  {  // finalize x (t = hp*64+d); second half of value == mask -> x==1
    const int hp = t >> 6, d = t & 63;
    const int h = hp >> 1, p = hp & 1;
    const float num = acc_l[hp * 64 + d];
    const float den = acc_l[256 + hp * 64 + d];
    const float sxv = acc_l[512 + d];
    float x1, x2;
    if (den > 0.f) { x1 = num / den; x2 = 1.f; }
    else           { x1 = sxv * (1.f / (float)LL); x2 = 0.f; }  // uniform fallback
    x_lds[p * 256 + h * 128 + d] = x1;
    x_lds[p * 256 + h * 128 + 64 + d] = x2;
  }
  __syncthreads();

  {  // coeffs split-k: t = kh*128 + p*64 + j
    const int kh = t >> 7, pj = t & 127, p = pj >> 6, j = pj & 63;
    float acc = (kh == 0) ? out_b[j] : 0.f;
    const float* xp = &x_lds[p * 256 + kh * 128];
    const float* wp = out_w + (size_t)kh * 128 * 64 + j;
    for (int k = 0; k < 128; ++k) acc += xp[k] * wp[k * 64];
    cred[t] = acc;
  }
  __syncthreads();
  if (t < 128) {
    const float c = cred[t] + cred[t + 128];
    c_lds[t] = c;
    if (blockIdx.x == 0)
      out[(size_t)BB * TT * DD + b * 128 + t] = c;  // fp32 coeffs output
  }
  __syncthreads();
  if (t < 128) {  // A,B split-j: t = jh*64 + k
    const int jh = t >> 6, k = t & 63;
    float a = 0.f, bb = 0.f;
    const float* cp = &c_lds[jh * 32];
    const float* cp2 = &c_lds[64 + jh * 32];
    for (int j = 0; j < 32; ++j) {
      const float w1 = dec_w1[(jh * 32 + j) * 64 + k];
      a += cp[j] * w1;
      bb += cp2[j] * w1;
    }
    abred[t * 2] = a;
    abred[t * 2 + 1] = bb;
  }
  __syncthreads();
  if (t < 64) {
    ABl[t]      = dec_b1[t] + abred[t * 2]     + abred[(64 + t) * 2];
    ABl[64 + t] =             abred[t * 2 + 1] + abred[(64 + t) * 2 + 1];
  }
  __syncthreads();

  const int tl = t >> 4, dg = t & 15;  // 16 t's x 16 d-groups(4 d each)
  for (int it = 0; it < 4; ++it) {
    {  // phase A: h1 for 16 t's (1024 values, 4 per thread)
      int idx = t;
#pragma unroll
      for (int rr = 0; rr < 4; ++rr, idx += 256) {
        const int tl2 = idx >> 6, k = idx & 63;
        h1l[idx] = fmaxf(ABl[k] + yl[it * 16 + tl2] * ABl[64 + k], 0.f);
      }
    }
    __syncthreads();
    {  // phase B: out tile
      float a0 = b2l[dg * 4], a1 = b2l[dg * 4 + 1],
            a2 = b2l[dg * 4 + 2], a3 = b2l[dg * 4 + 3];
      const float4* w4 = (const float4*)w2l;
      const float* h1p = &h1l[tl * 64];
      for (int k = 0; k < 64; ++k) {
        const float h = h1p[k];
        const float4 w = w4[k * 16 + dg];
        a0 += h * w.x; a1 += h * w.y; a2 += h * w.z; a3 += h * w.w;
      }
      const int tg = t0 + it * 16 + tl;
      const size_t off = ((size_t)b * TT + tg) * 64 + dg * 4;
      float4 o; o.x = a0; o.y = a1; o.z = a2; o.w = a3;
      *(float4*)(out + off) = o;
    }
    __syncthreads();
  }
}

// ---------------------------------------------------------------------------
extern "C" void kernel_launch(void* const* d_in, const int* in_sizes, int n_in,
                              void* d_out, int out_size, void* d_ws, size_t ws_size,
                              hipStream_t stream) {
  const float* ts     = (const float*)d_in[0];
  const float* X      = (const float*)d_in[1];
  const float* M      = (const float*)d_in[2];
  const float* yts    = (const float*)d_in[3];
  const float* te_w   = (const float*)d_in[4];
  const float* te_b   = (const float*)d_in[5];
  const float* query  = (const float*)d_in[6];
  const float* qm_w   = (const float*)d_in[7];
  const float* qm_b   = (const float*)d_in[8];
  const float* km_w   = (const float*)d_in[9];
  const float* km_b   = (const float*)d_in[10];
  const float* out_w  = (const float*)d_in[11];
  const float* out_b  = (const float*)d_in[12];
  const float* dec_w1 = (const float*)d_in[13];
  const float* dec_b1 = (const float*)d_in[14];
  const float* dec_w2 = (const float*)d_in[15];
  const float* dec_b2 = (const float*)d_in[16];
  float* ws = (float*)d_ws;
  float* out = (float*)d_out;

  k_attn<<<dim3(NCHUNK, BB), 256, 0, stream>>>(
      ts, X, M, te_w, te_b, query, qm_w, qm_b, km_w, km_b, ws);
  k_dec<<<dim3(TT / 64, BB), 256, 0, stream>>>(
      yts, out_w, out_b, dec_w1, dec_b1, dec_w2, dec_b2, ws, out);
}